// Round 9
// baseline (404.558 us; speedup 1.0000x reference)
//
#include <hip/hip_runtime.h>
#include <stdint.h>

#define BB 4
#define TT 4096
#define DD 64
#define KBLK 64

typedef short short8 __attribute__((ext_vector_type(8)));
typedef float f32x4 __attribute__((ext_vector_type(4)));
typedef uint32_t u32x4 __attribute__((ext_vector_type(4)));

__device__ __forceinline__ uint16_t f2bf(float x) {
  uint32_t u = __float_as_uint(x);
  u += 0x7FFFu + ((u >> 16) & 1u);
  return (uint16_t)(u >> 16);
}
__device__ __forceinline__ float bf2f(uint16_t h) {
  return __uint_as_float(((uint32_t)h) << 16);
}
__device__ __forceinline__ uint32_t pkbf(float a, float b) {
  return (uint32_t)f2bf(a) | ((uint32_t)f2bf(b) << 16);
}

#define MFMA(a, b, c) __builtin_amdgcn_mfma_f32_16x16x32_bf16((a), (b), (c), 0, 0, 0)

// ---- pre-pass: fp32 -> bf16 hi/lo (Q scaled by 1/64 exactly), V transposed to [B][D][T] ----
__global__ __launch_bounds__(256) void prep_kernel(
    const float* __restrict__ Q, const float* __restrict__ K, const float* __restrict__ V,
    uint16_t* __restrict__ Qh, uint16_t* __restrict__ Ql,
    uint16_t* __restrict__ Kh, uint16_t* __restrict__ Kl,
    uint16_t* __restrict__ Vh, uint16_t* __restrict__ Vl) {
  __shared__ float vt[64][65];
  const int blk = blockIdx.x;  // 256 blocks: (b, 64-row tile)
  const int b = blk >> 6;
  const int r0 = (blk & 63) << 6;
  const int t = threadIdx.x;
  const size_t base = ((size_t)b * TT + r0) * DD;
  for (int i = t; i < 64 * 64; i += 256) {
    float q = Q[base + i] * 0.015625f;  // fold 1/dk scale (exact, pow2)
    uint16_t h = f2bf(q);
    Qh[base + i] = h;
    Ql[base + i] = f2bf(q - bf2f(h));
    float k = K[base + i];
    h = f2bf(k);
    Kh[base + i] = h;
    Kl[base + i] = f2bf(k - bf2f(h));
    int r = i >> 6, c = i & 63;
    vt[r][c] = V[base + i];
  }
  __syncthreads();
  for (int i = t; i < 64 * 64; i += 256) {
    int d = i >> 6, c = i & 63;  // c = local key index
    float v = vt[c][d];
    uint16_t h = f2bf(v);
    size_t o = ((size_t)b * DD + d) * TT + r0 + c;
    Vh[o] = h;
    Vl[o] = f2bf(v - bf2f(h));
  }
}

// ==== flash-attention fwd: split-K, S^T layout, dbuf LDS + global_load_lds DMA ====
// LDS per array: [64 rows][8 slots x 16B] linear (8 KiB). Swizzle: LDS(row,slot)
// holds source slot slot^(row&7) -- applied via per-lane SOURCE address at DMA
// time (linear dest as required by global_load_lds) and via XOR on the read side.
// One barrier per tile; DMA for t+1 issued before compute of t (drain hidden).
// P routed lane->lane via 32 shfl (no P LDS). Total LDS 64 KiB -> 2 blocks/CU.

// stage one 64x64 bf16 tile pair (K:[key][d], V:[d][key]) into LDS buffers
#define STAGE(KH, KL, VH, VL, S0)                                              \
  do {                                                                         \
    _Pragma("unroll") for (int c = t; c < 512; c += NW * 64) {                 \
      const int cb8 = (c & ~63) * 8; /* wave-uniform LDS elem base */          \
      const int row = c >> 3;                                                  \
      const int ssl = (c & 7) ^ (row & 7);                                     \
      const size_t ksrc = kvb + (size_t)((S0) + row) * DD + ssl * 8;           \
      const size_t vsrc = vtb + (size_t)row * TT + (S0) + ssl * 8;             \
      __builtin_amdgcn_global_load_lds(Kh + ksrc, &KH[cb8], 16, 0, 0);         \
      __builtin_amdgcn_global_load_lds(Kl + ksrc, &KL[cb8], 16, 0, 0);         \
      __builtin_amdgcn_global_load_lds(Vh + vsrc, &VH[cb8], 16, 0, 0);         \
      __builtin_amdgcn_global_load_lds(Vl + vsrc, &VL[cb8], 16, 0, 0);         \
    }                                                                          \
  } while (0)

#define LOADMASK(MK, TILE)                                                     \
  do {                                                                         \
    _Pragma("unroll") for (int q_ = 0; q_ < 4; ++q_)                           \
        MK[q_] = __builtin_nontemporal_load(                                   \
            (const f32x4*)(mprow + (size_t)(TILE) * KBLK + q_ * 16));          \
  } while (0)

#define LOADMASK_Z(MK)                                                         \
  do {                                                                         \
    _Pragma("unroll") for (int q_ = 0; q_ < 4; ++q_)                           \
        MK[q_] = (f32x4){0.f, 0.f, 0.f, 0.f};                                  \
  } while (0)

#define PACK(TT_, HA, HB, LA, LB)                                              \
  {                                                                            \
    const float a0 = s_[TT_][0], a1 = s_[TT_][1];                              \
    const float a2 = s_[TT_][2], a3 = s_[TT_][3];                              \
    const uint16_t h0 = f2bf(a0), h1 = f2bf(a1);                               \
    const uint16_t h2 = f2bf(a2), h3 = f2bf(a3);                               \
    HA = (uint32_t)h0 | ((uint32_t)h1 << 16);                                  \
    HB = (uint32_t)h2 | ((uint32_t)h3 << 16);                                  \
    LA = pkbf(a0 - bf2f(h0), a1 - bf2f(h1));                                   \
    LB = pkbf(a2 - bf2f(h2), a3 - bf2f(h3));                                   \
  }

// exchange: target lane (lr,lq) builds 4 u32 = keys 32c+8lq+0..7 (q=lr) from
// source lanes src0/src1 registers tt=2c+(lq>>1) (select-after-shuffle).
#define XCHG(W, SA0, SB0, SA1, SB1)                                            \
  {                                                                            \
    const uint32_t A0 = __shfl(SA0, src0), A1 = __shfl(SB0, src0);             \
    const uint32_t B0 = __shfl(SA1, src0), B1 = __shfl(SB1, src0);             \
    const uint32_t A2 = __shfl(SA0, src1), A3 = __shfl(SB0, src1);             \
    const uint32_t B2 = __shfl(SA1, src1), B3 = __shfl(SB1, src1);             \
    W = (u32x4){hi2 ? B0 : A0, hi2 ? B1 : A1, hi2 ? B2 : A2, hi2 ? B3 : A3};   \
  }

#define COMPUTE(KH, KL, VH, VL, MK)                                            \
  do {                                                                         \
    f32x4 s_[4];                                                               \
    _Pragma("unroll") for (int tt = 0; tt < 4; ++tt) {                         \
      f32x4 acc = (f32x4){0.f, 0.f, 0.f, 0.f};                                 \
      const short8 bh0 = *(const short8*)&KH[(tt * 16 + lr) * 64 + sw0 * 8];   \
      const short8 bl0 = *(const short8*)&KL[(tt * 16 + lr) * 64 + sw0 * 8];   \
      acc = MFMA(bh0, qh[0], acc);                                             \
      acc = MFMA(bl0, qh[0], acc);                                             \
      acc = MFMA(bh0, ql[0], acc);                                             \
      const short8 bh1 = *(const short8*)&KH[(tt * 16 + lr) * 64 + sw1 * 8];   \
      const short8 bl1 = *(const short8*)&KL[(tt * 16 + lr) * 64 + sw1 * 8];   \
      acc = MFMA(bh1, qh[1], acc);                                             \
      acc = MFMA(bl1, qh[1], acc);                                             \
      acc = MFMA(bh1, ql[1], acc);                                             \
      s_[tt] = acc + MK[tt];                                                   \
    }                                                                          \
    float cm = fmaxf(fmaxf(fmaxf(s_[0][0], s_[0][1]), fmaxf(s_[0][2], s_[0][3])), \
                     fmaxf(fmaxf(s_[1][0], s_[1][1]), fmaxf(s_[1][2], s_[1][3]))); \
    cm = fmaxf(cm, fmaxf(fmaxf(fmaxf(s_[2][0], s_[2][1]), fmaxf(s_[2][2], s_[2][3])), \
                         fmaxf(fmaxf(s_[3][0], s_[3][1]), fmaxf(s_[3][2], s_[3][3])))); \
    cm = fmaxf(cm, __shfl_xor(cm, 16));                                        \
    cm = fmaxf(cm, __shfl_xor(cm, 32));                                        \
    if (!__all(cm <= mrow + 8.0f)) { /* defer-max (T13) */                     \
      const float mn = fmaxf(mrow, cm);                                        \
      const float scl = __expf(mrow - mn);                                     \
      mrow = mn;                                                               \
      lrow *= scl;                                                             \
      float sj0 = __shfl(scl, lq * 4 + 0), sj1 = __shfl(scl, lq * 4 + 1);      \
      float sj2 = __shfl(scl, lq * 4 + 2), sj3 = __shfl(scl, lq * 4 + 3);      \
      _Pragma("unroll") for (int dt = 0; dt < 4; ++dt) {                       \
        o[dt][0] *= sj0; o[dt][1] *= sj1; o[dt][2] *= sj2; o[dt][3] *= sj3;    \
      }                                                                        \
    }                                                                          \
    _Pragma("unroll") for (int tt = 0; tt < 4; ++tt)                           \
        _Pragma("unroll") for (int j = 0; j < 4; ++j)                          \
            s_[tt][j] = __expf(s_[tt][j] - mrow);                              \
    float rs = ((s_[0][0] + s_[0][1]) + (s_[0][2] + s_[0][3])) +               \
               ((s_[1][0] + s_[1][1]) + (s_[1][2] + s_[1][3])) +               \
               ((s_[2][0] + s_[2][1]) + (s_[2][2] + s_[2][3])) +               \
               ((s_[3][0] + s_[3][1]) + (s_[3][2] + s_[3][3]));                \
    rs += __shfl_xor(rs, 16);                                                  \
    rs += __shfl_xor(rs, 32);                                                  \
    lrow += rs;                                                                \
    uint32_t H0a, H0b, L0a, L0b, H1a, H1b, L1a, L1b;                           \
    uint32_t H2a, H2b, L2a, L2b, H3a, H3b, L3a, L3b;                           \
    PACK(0, H0a, H0b, L0a, L0b)                                                \
    PACK(1, H1a, H1b, L1a, L1b)                                                \
    PACK(2, H2a, H2b, L2a, L2b)                                                \
    PACK(3, H3a, H3b, L3a, L3b)                                                \
    u32x4 wh0, wl0, wh1, wl1;                                                  \
    XCHG(wh0, H0a, H0b, H1a, H1b)                                              \
    XCHG(wl0, L0a, L0b, L1a, L1b)                                              \
    XCHG(wh1, H2a, H2b, H3a, H3b)                                              \
    XCHG(wl1, L2a, L2b, L3a, L3b)                                              \
    const short8 ph0 = __builtin_bit_cast(short8, wh0);                        \
    const short8 pl0 = __builtin_bit_cast(short8, wl0);                        \
    const short8 ph1 = __builtin_bit_cast(short8, wh1);                        \
    const short8 pl1 = __builtin_bit_cast(short8, wl1);                        \
    _Pragma("unroll") for (int dt = 0; dt < 4; ++dt) {                         \
      const short8 vh = *(const short8*)&VH[(dt * 16 + lr) * 64 + sw0 * 8];    \
      const short8 vl = *(const short8*)&VL[(dt * 16 + lr) * 64 + sw0 * 8];    \
      o[dt] = MFMA(ph0, vh, o[dt]);                                            \
      o[dt] = MFMA(pl0, vh, o[dt]);                                            \
      o[dt] = MFMA(ph0, vl, o[dt]);                                            \
    }                                                                          \
    _Pragma("unroll") for (int dt = 0; dt < 4; ++dt) {                         \
      const short8 vh = *(const short8*)&VH[(dt * 16 + lr) * 64 + sw1 * 8];    \
      const short8 vl = *(const short8*)&VL[(dt * 16 + lr) * 64 + sw1 * 8];    \
      o[dt] = MFMA(ph1, vh, o[dt]);                                            \
      o[dt] = MFMA(pl1, vh, o[dt]);                                            \
      o[dt] = MFMA(ph1, vl, o[dt]);                                            \
    }                                                                          \
  } while (0)

template <int NSEG, int NW>
__global__ __launch_bounds__(NW * 64, 4) void attn_kernel(
    const float* __restrict__ mask, float* __restrict__ out,
    float* __restrict__ Op, float* __restrict__ Mp, float* __restrict__ Lp,
    const uint16_t* __restrict__ Qh, const uint16_t* __restrict__ Ql,
    const uint16_t* __restrict__ Kh, const uint16_t* __restrict__ Kl,
    const uint16_t* __restrict__ Vh, const uint16_t* __restrict__ Vl) {
  constexpr int RPB = NW * 16;
  constexpr int PBH = (TT / RPB) / 2;
  constexpr int SEGLEN = TT / NSEG;
  constexpr int NIT = SEGLEN / KBLK;
  static_assert((NIT & 1) == 0, "NIT must be even for 2x-unrolled dbuf");

  // double-buffered K/V: distinct static arrays so AA proves DMA !alias reads
  __shared__ uint16_t KhA[4096], KlA[4096], VhA[4096], VlA[4096];
  __shared__ uint16_t KhB[4096], KlB[4096], VhB[4096], VlB[4096];

  const int bid = blockIdx.x;
  const int xcd = bid & 7;  // batch -> XCD pair; K/V set 2 MiB per XCD-pair L2
  const int b = xcd >> 1;
  const int u = bid >> 3;
  const int rbl = (u % PBH) * 2 + (xcd & 1);
  const int seg = u / PBH;
  const int q0 = rbl * RPB;
  const int t = threadIdx.x;
  const int w = t >> 6;
  const int l = t & 63;
  const int lr = l & 15;
  const int lq = l >> 4;
  const int qrow = q0 + w * 16;
  const int sb = seg * SEGLEN;

  // read-side swizzled slot indices (c=0 / c=1)
  const int sw0 = lq ^ (lr & 7);
  const int sw1 = sw0 ^ 4;
  // P-exchange source lanes + select bit
  const int src0 = lr + (((2 * lq) & 3) << 4);
  const int src1 = lr + (((2 * lq + 1) & 3) << 4);
  const int hi2 = lq >> 1;

  // Q fragment (B-operand of S^T): col(q)=lr, k(d)=c*32+lq*8+[0..7]
  const uint16_t* qhp = Qh + ((size_t)b * TT + qrow + lr) * DD + lq * 8;
  const uint16_t* qlp = Ql + ((size_t)b * TT + qrow + lr) * DD + lq * 8;
  short8 qh[2], ql[2];
  qh[0] = *(const short8*)(qhp);
  qh[1] = *(const short8*)(qhp + 32);
  ql[0] = *(const short8*)(qlp);
  ql[1] = *(const short8*)(qlp + 32);

  f32x4 o[4];
  float mrow = -1e30f, lrow = 0.f;  // per-lane: q-row = lr
#pragma unroll
  for (int dt = 0; dt < 4; ++dt) o[dt] = (f32x4){0.f, 0.f, 0.f, 0.f};

  const float* mprow = mask + ((size_t)b * TT + qrow + lr) * TT + sb + lq * 4;
  const size_t kvb = (size_t)b * TT * DD;
  const size_t vtb = (size_t)b * DD * TT;

  f32x4 mk0[4], mk1[4];
  // prologue: tile 0 -> buf A; mask tile 0
  STAGE(KhA, KlA, VhA, VlA, sb);
  LOADMASK(mk0, 0);
  __syncthreads();  // drains DMA + mask

  for (int itp = 0; itp < NIT / 2; ++itp) {
    const int it0 = 2 * itp;
    // body A: stage it0+1 -> B (in flight under compute), compute it0 from A
    STAGE(KhB, KlB, VhB, VlB, sb + (it0 + 1) * KBLK);
    LOADMASK(mk1, it0 + 1);
    COMPUTE(KhA, KlA, VhA, VlA, mk0);
    __syncthreads();
    // body B: stage it0+2 -> A, compute it0+1 from B
    if (it0 + 2 < NIT) {
      STAGE(KhA, KlA, VhA, VlA, sb + (it0 + 2) * KBLK);
      LOADMASK(mk0, it0 + 2);
    } else {
      LOADMASK_Z(mk0);
    }
    COMPUTE(KhB, KlB, VhB, VlB, mk1);
    __syncthreads();
  }

  // epilogue: O layout q=lq*4+j, d=dt*16+lr; l/m live on lane lr=q
  if constexpr (NSEG == 1) {
    const float linv = 1.0f / lrow;
#pragma unroll
    for (int j = 0; j < 4; ++j) {
      const float inv = __shfl(linv, lq * 4 + j);
      const size_t ob = ((size_t)b * TT + qrow + lq * 4 + j) * DD + lr;
#pragma unroll
      for (int dt = 0; dt < 4; ++dt) out[ob + dt * 16] = o[dt][j] * inv;
    }
  } else {
    const int grow = b * TT + qrow;
#pragma unroll
    for (int j = 0; j < 4; ++j) {
      const size_t r = (size_t)seg * (BB * TT) + grow + lq * 4 + j;
#pragma unroll
      for (int dt = 0; dt < 4; ++dt) Op[r * 64 + dt * 16 + lr] = o[dt][j];
    }
    if (lq == 0) {
      const size_t r = (size_t)seg * (BB * TT) + grow + lr;
      Mp[r] = mrow;
      Lp[r] = lrow;
    }
  }
}

// ---- merge NSEG partial results per row ----
__global__ __launch_bounds__(256) void combine_kernel(
    const float* __restrict__ Op, const float* __restrict__ Mp,
    const float* __restrict__ Lp, float* __restrict__ out, int nseg) {
  const int gid = blockIdx.x * 256 + threadIdx.x;
  const int r = gid >> 6, d = gid & 63;
  constexpr int ROWS = BB * TT;
  float m = -3.0e38f;
  for (int s = 0; s < nseg; ++s) m = fmaxf(m, Mp[s * ROWS + r]);
  float num = 0.f, den = 0.f;
  for (int s = 0; s < nseg; ++s) {
    const float e = __expf(Mp[s * ROWS + r] - m);
    den += Lp[s * ROWS + r] * e;
    num += Op[((size_t)s * ROWS + r) * 64 + d] * e;
  }
  out[(size_t)r * 64 + d] = num / den;
}

extern "C" void kernel_launch(void* const* d_in, const int* in_sizes, int n_in,
                              void* d_out, int out_size, void* d_ws, size_t ws_size,
                              hipStream_t stream) {
  const float* Q = (const float*)d_in[0];
  const float* K = (const float*)d_in[1];
  const float* V = (const float*)d_in[2];
  const float* mask = (const float*)d_in[3];
  float* out = (float*)d_out;

  const size_t NE = (size_t)BB * TT * DD;  // 1M elements per array
  const size_t ROWS = (size_t)BB * TT;     // 16384
  uint16_t* ws = (uint16_t*)d_ws;          // bf16 arrays: 12 MiB
  uint16_t* Qh = ws;
  uint16_t* Ql = ws + NE;
  uint16_t* Kh = ws + 2 * NE;
  uint16_t* Kl = ws + 3 * NE;
  uint16_t* Vh = ws + 4 * NE;
  uint16_t* Vl = ws + 5 * NE;

  const size_t bf_bytes = 6 * NE * 2;
  const size_t per_seg = ROWS * 64 * 4 + ROWS * 2 * 4;  // O + (m,l)
  int nseg = (ws_size >= bf_bytes + 4 * per_seg) ? 4
           : (ws_size >= bf_bytes + 2 * per_seg) ? 2 : 1;

  char* pbase = (char*)d_ws + bf_bytes;
  float* Op = (float*)pbase;
  float* Mp = (float*)(pbase + (size_t)nseg * ROWS * 64 * 4);
  float* Lp = Mp + (size_t)nseg * ROWS;

  prep_kernel<<<dim3(256), dim3(256), 0, stream>>>(Q, K, V, Qh, Ql, Kh, Kl, Vh, Vl);

  if (nseg == 4) {
    attn_kernel<4, 8><<<dim3(512), dim3(512), 0, stream>>>(
        mask, out, Op, Mp, Lp, Qh, Ql, Kh, Kl, Vh, Vl);
  } else if (nseg == 2) {
    attn_kernel<2, 8><<<dim3(256), dim3(512), 0, stream>>>(
        mask, out, Op, Mp, Lp, Qh, Ql, Kh, Kl, Vh, Vl);
  } else {
    attn_kernel<1, 4><<<dim3(256), dim3(256), 0, stream>>>(
        mask, out, Op, Mp, Lp, Qh, Ql, Kh, Kl, Vh, Vl);
  }
  if (nseg > 1) {
    combine_kernel<<<dim3((ROWS * 64) / 256), dim3(256), 0, stream>>>(Op, Mp, Lp, out, nseg);
  }
}